// Round 2
// baseline (562.212 us; speedup 1.0000x reference)
//
#include <hip/hip_runtime.h>
#include <stdint.h>

typedef unsigned short u16;
typedef __attribute__((ext_vector_type(8))) short short8;   // 8 bf16 = 4 VGPRs (MFMA A/B frag)
typedef __attribute__((ext_vector_type(4))) float f32x4;    // MFMA C/D frag

#define LOG2E 1.4426950408889634f
#define NT 8192
#define DH 256

// ---- workspace layout (u16 element offsets) ----
// persistent across flash:
#define QH  0
#define QL  2097152
#define KH  4194304
#define VTB 6291456            // V transposed: [256][8192]
// temps (dead after k_qkv; overlapped by OPART during k_flash):
#define XH0 8388608
#define XL0 10485760
#define XH1 12582912
#define XL1 14680064
#define XH2 16777216
#define XL2 18874368
#define WQH 20971520
#define WQL 21037056
#define WKH 21102592
#define WKL 21168128
#define WVH 21233664
#define WVL 21299200
// fp32 region (float element offsets):
#define OPART_F 4194304        // byte 16,777,216: 4 x [8192][256] unnormalized partial O
#define MPART_F 12582912       // 4 x [8192] running max
#define LPART_F 12615680       // 4 x [8192] running denom
// total ws bytes used: ~50.6 MB

__device__ __forceinline__ u16 f2bf(float f) {
  union { float f; uint32_t u; } c; c.f = f;
  uint32_t u = c.u;
  return (u16)((u + 0x7fffu + ((u >> 16) & 1)) >> 16);   // RNE
}
__device__ __forceinline__ float bf2f(u16 h) {
  union { uint32_t u; float f; } c; c.u = ((uint32_t)h) << 16;
  return c.f;
}

// XOR swizzle for LDS rows of 32 16B-units (512B rows): balances ds_read_b128 banks
__device__ __forceinline__ int swz32(int u, int row) {
  return (u & 24) | ((u & 7) ^ (row & 7));
}

__device__ __forceinline__ f32x4 mfma16(short8 a, short8 b, f32x4 c) {
  return __builtin_amdgcn_mfma_f32_16x16x32_bf16(a, b, c, 0, 0, 0);
}

// ---------------- kernel 1: fp32 -> hi/lo bf16 split ----------------
__global__ __launch_bounds__(256) void k_convert(
    const float* __restrict__ x1, const float* __restrict__ x2, const float* __restrict__ x3,
    const float* __restrict__ wq, const float* __restrict__ wk, const float* __restrict__ wv,
    u16* __restrict__ wsu) {
  int b = blockIdx.x;
  const float* src; u16 *dh, *dl; int bl;
  if (b < 1024)      { src = x1; dh = wsu + XH0; dl = wsu + XL0; bl = b; }
  else if (b < 2048) { src = x2; dh = wsu + XH1; dl = wsu + XL1; bl = b - 1024; }
  else if (b < 3072) { src = x3; dh = wsu + XH2; dl = wsu + XL2; bl = b - 2048; }
  else if (b < 3104) { src = wq; dh = wsu + WQH; dl = wsu + WQL; bl = b - 3072; }
  else if (b < 3136) { src = wk; dh = wsu + WKH; dl = wsu + WKL; bl = b - 3104; }
  else               { src = wv; dh = wsu + WVH; dl = wsu + WVL; bl = b - 3136; }
  int i = (bl * 256 + threadIdx.x) * 8;
  f32x4 a = *(const f32x4*)(src + i);
  f32x4 c = *(const f32x4*)(src + i + 4);
  short8 rh, rl;
  float v[8] = {a[0], a[1], a[2], a[3], c[0], c[1], c[2], c[3]};
#pragma unroll
  for (int j = 0; j < 8; j++) {
    u16 h = f2bf(v[j]);
    rh[j] = (short)h;
    rl[j] = (short)f2bf(v[j] - bf2f(h));
  }
  *(short8*)(dh + i) = rh;
  *(short8*)(dl + i) = rl;
}

// ---------------- kernel 2: QKV projection (NT gemm, 3-term hi/lo bf16 MFMA) ----------------
// out[m][n] = sum_k A[m][k] * B[n][k] + bias, A = Ah+Al, B = Bh+Bl (lo*lo dropped)
// mid 0: Q = x1 @ Wq^T + bq   -> QH/QL hi-lo pair [8192][256]
// mid 1: K = x2 @ Wk^T + bk   -> KH bf16 [8192][256]
// mid 2: Vt = Wv @ x3^T + bv  -> VTB bf16 [256][8192] (bias per row) == V transposed
__global__ __launch_bounds__(256) void k_qkv(
    u16* __restrict__ wsu,
    const float* __restrict__ bq, const float* __restrict__ bk, const float* __restrict__ bv) {
  __shared__ u16 sAh[64 * 256];   // 32 KB
  __shared__ u16 sAl[64 * 256];   // 32 KB
  __shared__ u16 sBh[32 * 256];   // 16 KB
  __shared__ u16 sBl[32 * 256];   // 16 KB
  int bx = blockIdx.x;
  int mid = bx >> 10;
  int t = bx & 1023;
  const u16 *Ah, *Al, *Bh, *Bl; u16 *Ohi, *Olo; const float* bias;
  int rb, cb, ldO, biasRow, writeLo;
  if (mid == 0) {
    Ah = wsu + XH0; Al = wsu + XL0; Bh = wsu + WQH; Bl = wsu + WQL;
    Ohi = wsu + QH; Olo = wsu + QL; bias = bq; biasRow = 0; writeLo = 1; ldO = 256;
    rb = t >> 3; cb = t & 7;
  } else if (mid == 1) {
    Ah = wsu + XH1; Al = wsu + XL1; Bh = wsu + WKH; Bl = wsu + WKL;
    Ohi = wsu + KH; Olo = nullptr; bias = bk; biasRow = 0; writeLo = 0; ldO = 256;
    rb = t >> 3; cb = t & 7;
  } else {
    Ah = wsu + WVH; Al = wsu + WVL; Bh = wsu + XH2; Bl = wsu + XL2;
    Ohi = wsu + VTB; Olo = nullptr; bias = bv; biasRow = 1; writeLo = 0; ldO = 8192;
    rb = t >> 8; cb = t & 255;
  }

  int tid = threadIdx.x;
#pragma unroll
  for (int i = 0; i < 8; i++) {            // stage A hi/lo: 64 rows x 32 units each
    int L = i * 256 + tid;
    int row = L >> 5, u = L & 31;
    short8 vh = *(const short8*)(Ah + (rb * 64 + row) * 256 + u * 8);
    short8 vl = *(const short8*)(Al + (rb * 64 + row) * 256 + u * 8);
    *(short8*)(&sAh[row * 256 + swz32(u, row) * 8]) = vh;
    *(short8*)(&sAl[row * 256 + swz32(u, row) * 8]) = vl;
  }
#pragma unroll
  for (int i = 0; i < 4; i++) {            // stage B hi/lo: 32 rows x 32 units each
    int L = i * 256 + tid;
    int row = L >> 5, u = L & 31;
    short8 vh = *(const short8*)(Bh + (cb * 32 + row) * 256 + u * 8);
    short8 vl = *(const short8*)(Bl + (cb * 32 + row) * 256 + u * 8);
    *(short8*)(&sBh[row * 256 + swz32(u, row) * 8]) = vh;
    *(short8*)(&sBl[row * 256 + swz32(u, row) * 8]) = vl;
  }
  __syncthreads();

  int lane = tid & 63, wave = tid >> 6;
  int n = lane & 15, quad = lane >> 4;
  int wm = wave >> 1, wn = wave & 1;       // wave tile: 32 rows x 16 cols
  f32x4 acc0 = {0.f,0.f,0.f,0.f}, acc1 = {0.f,0.f,0.f,0.f};
#pragma unroll
  for (int kk = 0; kk < 8; kk++) {
    int ra = wm * 32 + n;
    int sa0 = ra * 256 + swz32(kk * 4 + quad, ra) * 8;
    int sa1 = (ra + 16) * 256 + swz32(kk * 4 + quad, ra + 16) * 8;
    short8 a0h = *(const short8*)(&sAh[sa0]);
    short8 a1h = *(const short8*)(&sAh[sa1]);
    short8 a0l = *(const short8*)(&sAl[sa0]);
    short8 a1l = *(const short8*)(&sAl[sa1]);
    int rbB = wn * 16 + n;
    int sb = rbB * 256 + swz32(kk * 4 + quad, rbB) * 8;
    short8 bh = *(const short8*)(&sBh[sb]);
    short8 bl = *(const short8*)(&sBl[sb]);
    acc0 = mfma16(a0h, bh, acc0);
    acc1 = mfma16(a1h, bh, acc1);
    acc0 = mfma16(a0h, bl, acc0);
    acc1 = mfma16(a1h, bl, acc1);
    acc0 = mfma16(a0l, bh, acc0);
    acc1 = mfma16(a1l, bh, acc1);
  }
  int colg = cb * 32 + wn * 16 + n;
  float bcol = biasRow ? 0.0f : bias[colg];
#pragma unroll
  for (int mt = 0; mt < 2; mt++) {
    f32x4 acc = mt ? acc1 : acc0;
#pragma unroll
    for (int r = 0; r < 4; r++) {
      int rowg = rb * 64 + wm * 32 + mt * 16 + quad * 4 + r;
      float bb = biasRow ? bias[rowg] : bcol;
      float q = acc[r] + bb;
      u16 h = f2bf(q);
      Ohi[rowg * ldO + colg] = h;
      if (writeLo) Olo[rowg * ldO + colg] = f2bf(q - bf2f(h));
    }
  }
}

// ---------------- kernel 3: flash attention (split-K over keys) ----------------
// grid: 256 blocks = 64 q-blocks x 4 key-splits; 256 thr = 4 waves x 32 q-rows each
// Q held in registers as hi/lo bf16 pair -> QK^T is 2-term (Q-side exact)
__global__ __launch_bounds__(256, 1) void k_flash(
    const u16* __restrict__ wsu, float* __restrict__ wsf) {
  __shared__ u16 sK[32 * 256];       // 16 KB: 32 keys x 256 d, swizzled
  __shared__ u16 sV[256 * 32];       // 16 KB: 256 d x 32 keys (V^T tile), swizzled
  __shared__ u16 sP[4 * 32 * 40];    // 10 KB: per-wave P tile, 32x32 padded to stride 40

  int qb = blockIdx.x >> 2, sp = blockIdx.x & 3;
  int tid = threadIdx.x, lane = tid & 63, wave = tid >> 6;
  int n = lane & 15, quad = lane >> 4;
  const u16* Qhp = wsu + QH;
  const u16* Qlp = wsu + QL;
  const u16* Kp  = wsu + KH;
  const u16* Vp  = wsu + VTB;

  // Q fragments in registers (A-layout: A[m=lane&15][k=quad*8+j]) — hi/lo, 128 VGPRs
  short8 qfh[2][8], qfl[2][8];
  int rowQ0 = qb * 128 + wave * 32 + n;
#pragma unroll
  for (int mt = 0; mt < 2; mt++)
#pragma unroll
    for (int kk = 0; kk < 8; kk++) {
      qfh[mt][kk] = *(const short8*)(Qhp + (rowQ0 + mt * 16) * 256 + kk * 32 + quad * 8);
      qfl[mt][kk] = *(const short8*)(Qlp + (rowQ0 + mt * 16) * 256 + kk * 32 + quad * 8);
    }

  f32x4 o[2][16];
#pragma unroll
  for (int mt = 0; mt < 2; mt++)
#pragma unroll
    for (int nt = 0; nt < 16; nt++) { o[mt][nt][0]=0.f; o[mt][nt][1]=0.f; o[mt][nt][2]=0.f; o[mt][nt][3]=0.f; }
  float mcur[8], lcur[8];
#pragma unroll
  for (int j = 0; j < 8; j++) { mcur[j] = -1e30f; lcur[j] = 0.f; }

  for (int it = 0; it < 64; it++) {
    int key0 = sp * 2048 + it * 32;
    __syncthreads();
    // stage K tile (1024 16B-units) and V^T tile (1024 units), 8 units/thread
#pragma unroll
    for (int i = 0; i < 4; i++) {
      int L = i * 256 + tid;
      int row = L >> 5, u = L & 31;
      short8 v = *(const short8*)(Kp + (key0 + row) * 256 + u * 8);
      *(short8*)(&sK[row * 256 + swz32(u, row) * 8]) = v;
    }
#pragma unroll
    for (int i = 0; i < 4; i++) {
      int L = i * 256 + tid;
      int d = L >> 2, u = L & 3;
      short8 v = *(const short8*)(Vp + d * 8192 + key0 + u * 8);
      *(short8*)(&sV[d * 32 + (u ^ (d & 3)) * 8]) = v;
    }
    __syncthreads();

    // S = Q K^T for this 32-key tile: 2 m-tiles x 2 n-tiles x 8 ksteps x 2 hi/lo terms
    f32x4 s[2][2];
#pragma unroll
    for (int mt = 0; mt < 2; mt++)
#pragma unroll
      for (int ntk = 0; ntk < 2; ntk++) { s[mt][ntk][0]=0.f; s[mt][ntk][1]=0.f; s[mt][ntk][2]=0.f; s[mt][ntk][3]=0.f; }
#pragma unroll
    for (int kk = 0; kk < 8; kk++) {
      short8 b0 = *(const short8*)(&sK[n * 256 + swz32(kk * 4 + quad, n) * 8]);
      short8 b1 = *(const short8*)(&sK[(n + 16) * 256 + swz32(kk * 4 + quad, n + 16) * 8]);
      s[0][0] = mfma16(qfh[0][kk], b0, s[0][0]);
      s[0][1] = mfma16(qfh[0][kk], b1, s[0][1]);
      s[1][0] = mfma16(qfh[1][kk], b0, s[1][0]);
      s[1][1] = mfma16(qfh[1][kk], b1, s[1][1]);
      s[0][0] = mfma16(qfl[0][kk], b0, s[0][0]);
      s[0][1] = mfma16(qfl[0][kk], b1, s[0][1]);
      s[1][0] = mfma16(qfl[1][kk], b0, s[1][0]);
      s[1][1] = mfma16(qfl[1][kk], b1, s[1][1]);
    }

    // online softmax: tile row-max (cross-lane over the 16 lanes sharing rows)
    float tm[8]; bool changed = false;
#pragma unroll
    for (int mt = 0; mt < 2; mt++)
#pragma unroll
      for (int r = 0; r < 4; r++) {
        float v = fmaxf(s[mt][0][r], s[mt][1][r]);
        v = fmaxf(v, __shfl_xor(v, 1));
        v = fmaxf(v, __shfl_xor(v, 2));
        v = fmaxf(v, __shfl_xor(v, 4));
        v = fmaxf(v, __shfl_xor(v, 8));
        int j = mt * 4 + r;
        tm[j] = v;
        if (v > mcur[j]) changed = true;
      }
    if (__ballot(changed)) {                    // lazy rescale: ~ln(64) times total
      float al[8];
#pragma unroll
      for (int j = 0; j < 8; j++) {
        float mn = fmaxf(mcur[j], tm[j]);
        al[j] = exp2f((mcur[j] - mn) * LOG2E);
        mcur[j] = mn;
        lcur[j] *= al[j];
      }
#pragma unroll
      for (int mt = 0; mt < 2; mt++)
#pragma unroll
        for (int nt = 0; nt < 16; nt++)
#pragma unroll
          for (int r = 0; r < 4; r++)
            o[mt][nt][r] *= al[mt * 4 + r];
    }

    // p = exp(s - m), accumulate per-lane partial l, write P to LDS (C->A transform)
    u16* myP = &sP[wave * 1280];
#pragma unroll
    for (int mt = 0; mt < 2; mt++)
#pragma unroll
      for (int ntk = 0; ntk < 2; ntk++)
#pragma unroll
        for (int r = 0; r < 4; r++) {
          int j = mt * 4 + r;
          float p = exp2f((s[mt][ntk][r] - mcur[j]) * LOG2E);
          lcur[j] += p;
          myP[(mt * 16 + quad * 4 + r) * 40 + ntk * 16 + n] = f2bf(p);
        }

    // PV: O[32 x 256] += P[32 x 32] @ V[32 x 256]  (single K=32 MFMA step)
    short8 pa0 = *(const short8*)(&myP[n * 40 + quad * 8]);
    short8 pa1 = *(const short8*)(&myP[(16 + n) * 40 + quad * 8]);
#pragma unroll
    for (int nt = 0; nt < 16; nt++) {
      int d = nt * 16 + n;
      short8 vb = *(const short8*)(&sV[d * 32 + (quad ^ (d & 3)) * 8]);
      o[0][nt] = mfma16(pa0, vb, o[0][nt]);
      o[1][nt] = mfma16(pa1, vb, o[1][nt]);
    }
  }

  // reduce l across the 16 lanes sharing rows
#pragma unroll
  for (int j = 0; j < 8; j++) {
    float v = lcur[j];
    v += __shfl_xor(v, 1); v += __shfl_xor(v, 2);
    v += __shfl_xor(v, 4); v += __shfl_xor(v, 8);
    lcur[j] = v;
  }

  // store unnormalized partials + stats
  float* op = wsf + OPART_F + (size_t)sp * (NT * DH);
  int rowb = qb * 128 + wave * 32;
#pragma unroll
  for (int mt = 0; mt < 2; mt++)
#pragma unroll
    for (int nt = 0; nt < 16; nt++)
#pragma unroll
      for (int r = 0; r < 4; r++) {
        int row = rowb + mt * 16 + quad * 4 + r;
        op[row * 256 + nt * 16 + n] = o[mt][nt][r];
      }
  if (n == 0) {
#pragma unroll
    for (int mt = 0; mt < 2; mt++)
#pragma unroll
      for (int r = 0; r < 4; r++) {
        int row = rowb + mt * 16 + quad * 4 + r;
        wsf[MPART_F + sp * NT + row] = mcur[mt * 4 + r];
        wsf[LPART_F + sp * NT + row] = lcur[mt * 4 + r];
      }
  }
}

// ---------------- kernel 4: combine splits ----------------
__global__ __launch_bounds__(256) void k_combine(
    const float* __restrict__ wsf, float* __restrict__ out) {
  int gid = blockIdx.x * 256 + threadIdx.x;
  int row = gid >> 6, cg = gid & 63;
  float m[4], l[4];
#pragma unroll
  for (int s = 0; s < 4; s++) {
    m[s] = wsf[MPART_F + s * NT + row];
    l[s] = wsf[LPART_F + s * NT + row];
  }
  float ms = fmaxf(fmaxf(m[0], m[1]), fmaxf(m[2], m[3]));
  float denom = 0.f;
  f32x4 acc = {0.f, 0.f, 0.f, 0.f};
#pragma unroll
  for (int s = 0; s < 4; s++) {
    float w = exp2f((m[s] - ms) * LOG2E);
    denom += w * l[s];
    f32x4 ov = *(const f32x4*)(wsf + OPART_F + ((size_t)s * NT + row) * 256 + cg * 4);
    acc[0] += w * ov[0]; acc[1] += w * ov[1];
    acc[2] += w * ov[2]; acc[3] += w * ov[3];
  }
  float inv = 1.0f / denom;
  f32x4 r = {acc[0] * inv, acc[1] * inv, acc[2] * inv, acc[3] * inv};
  *(f32x4*)(out + row * 256 + cg * 4) = r;
}

extern "C" void kernel_launch(void* const* d_in, const int* in_sizes, int n_in,
                              void* d_out, int out_size, void* d_ws, size_t ws_size,
                              hipStream_t stream) {
  const float* x1 = (const float*)d_in[0];
  const float* x2 = (const float*)d_in[1];
  const float* x3 = (const float*)d_in[2];
  const float* Wq = (const float*)d_in[3];
  const float* bq = (const float*)d_in[4];
  const float* Wk = (const float*)d_in[5];
  const float* bk = (const float*)d_in[6];
  const float* Wv = (const float*)d_in[7];
  const float* bv = (const float*)d_in[8];
  u16* wsu = (u16*)d_ws;
  float* wsf = (float*)d_ws;
  float* out = (float*)d_out;

  k_convert<<<dim3(3168), dim3(256), 0, stream>>>(x1, x2, x3, Wq, Wk, Wv, wsu);
  k_qkv<<<dim3(3072), dim3(256), 0, stream>>>(wsu, bq, bk, bv);
  k_flash<<<dim3(256), dim3(256), 0, stream>>>(wsu, wsf);
  k_combine<<<dim3(2048), dim3(256), 0, stream>>>(wsf, out);
}

// Round 3
// 285.010 us; speedup vs baseline: 1.9726x; 1.9726x over previous
//
#include <hip/hip_runtime.h>
#include <stdint.h>

typedef unsigned short u16;
typedef __attribute__((ext_vector_type(8))) short short8;   // 8 bf16 = 4 VGPRs (MFMA A/B frag)
typedef __attribute__((ext_vector_type(4))) float f32x4;    // MFMA C/D frag

#define LOG2E 1.4426950408889634f
#define NT 8192
#define DH 256

// ---- workspace layout (u16 element offsets) ----
#define QH  0
#define QL  2097152
#define KH  4194304
#define VTB 6291456            // V transposed: [256][8192]
#define XH0 8388608
#define XL0 10485760
#define XH1 12582912
#define XL1 14680064
#define XH2 16777216
#define XL2 18874368
#define WQH 20971520
#define WQL 21037056
#define WKH 21102592
#define WKL 21168128
#define WVH 21233664
#define WVL 21299200
// fp32 region (float element offsets):
#define OPART_F 4194304        // 4 x [8192][256] unnormalized partial O
#define MPART_F 12582912       // 4 x [8192] running max
#define LPART_F 12615680       // 4 x [8192] running denom

__device__ __forceinline__ u16 f2bf(float f) {
  union { float f; uint32_t u; } c; c.f = f;
  uint32_t u = c.u;
  return (u16)((u + 0x7fffu + ((u >> 16) & 1)) >> 16);   // RNE
}
__device__ __forceinline__ float bf2f(u16 h) {
  union { uint32_t u; float f; } c; c.u = ((uint32_t)h) << 16;
  return c.f;
}

// XOR swizzle for LDS rows of 32 16B-units (512B rows)
__device__ __forceinline__ int swz32(int u, int row) {
  return (u & 24) | ((u & 7) ^ (row & 7));
}

__device__ __forceinline__ f32x4 mfma16(short8 a, short8 b, f32x4 c) {
  return __builtin_amdgcn_mfma_f32_16x16x32_bf16(a, b, c, 0, 0, 0);
}

// async global->LDS, 16B per lane; LDS dest is wave-uniform base + lane*16
__device__ __forceinline__ void gl_lds16(const u16* g, u16* l) {
  __builtin_amdgcn_global_load_lds(
      (const __attribute__((address_space(1))) uint32_t*)g,
      (__attribute__((address_space(3))) uint32_t*)l, 16, 0, 0);
}

// ---------------- kernel 1: fp32 -> hi/lo bf16 split ----------------
__global__ __launch_bounds__(256) void k_convert(
    const float* __restrict__ x1, const float* __restrict__ x2, const float* __restrict__ x3,
    const float* __restrict__ wq, const float* __restrict__ wk, const float* __restrict__ wv,
    u16* __restrict__ wsu) {
  int b = blockIdx.x;
  const float* src; u16 *dh, *dl; int bl;
  if (b < 1024)      { src = x1; dh = wsu + XH0; dl = wsu + XL0; bl = b; }
  else if (b < 2048) { src = x2; dh = wsu + XH1; dl = wsu + XL1; bl = b - 1024; }
  else if (b < 3072) { src = x3; dh = wsu + XH2; dl = wsu + XL2; bl = b - 2048; }
  else if (b < 3104) { src = wq; dh = wsu + WQH; dl = wsu + WQL; bl = b - 3072; }
  else if (b < 3136) { src = wk; dh = wsu + WKH; dl = wsu + WKL; bl = b - 3104; }
  else               { src = wv; dh = wsu + WVH; dl = wsu + WVL; bl = b - 3136; }
  int i = (bl * 256 + threadIdx.x) * 8;
  f32x4 a = *(const f32x4*)(src + i);
  f32x4 c = *(const f32x4*)(src + i + 4);
  short8 rh, rl;
  float v[8] = {a[0], a[1], a[2], a[3], c[0], c[1], c[2], c[3]};
#pragma unroll
  for (int j = 0; j < 8; j++) {
    u16 h = f2bf(v[j]);
    rh[j] = (short)h;
    rl[j] = (short)f2bf(v[j] - bf2f(h));
  }
  *(short8*)(dh + i) = rh;
  *(short8*)(dl + i) = rl;
}

// ---------------- kernel 2: QKV projection (NT gemm, 3-term hi/lo bf16 MFMA) ----------------
__global__ __launch_bounds__(256) void k_qkv(
    u16* __restrict__ wsu,
    const float* __restrict__ bq, const float* __restrict__ bk, const float* __restrict__ bv) {
  __shared__ u16 sAh[64 * 256];
  __shared__ u16 sAl[64 * 256];
  __shared__ u16 sBh[32 * 256];
  __shared__ u16 sBl[32 * 256];
  int bx = blockIdx.x;
  int mid = bx >> 10;
  int t = bx & 1023;
  const u16 *Ah, *Al, *Bh, *Bl; u16 *Ohi, *Olo; const float* bias;
  int rb, cb, ldO, biasRow, writeLo;
  if (mid == 0) {
    Ah = wsu + XH0; Al = wsu + XL0; Bh = wsu + WQH; Bl = wsu + WQL;
    Ohi = wsu + QH; Olo = wsu + QL; bias = bq; biasRow = 0; writeLo = 1; ldO = 256;
    rb = t >> 3; cb = t & 7;
  } else if (mid == 1) {
    Ah = wsu + XH1; Al = wsu + XL1; Bh = wsu + WKH; Bl = wsu + WKL;
    Ohi = wsu + KH; Olo = nullptr; bias = bk; biasRow = 0; writeLo = 0; ldO = 256;
    rb = t >> 3; cb = t & 7;
  } else {
    Ah = wsu + WVH; Al = wsu + WVL; Bh = wsu + XH2; Bl = wsu + XL2;
    Ohi = wsu + VTB; Olo = nullptr; bias = bv; biasRow = 1; writeLo = 0; ldO = 8192;
    rb = t >> 8; cb = t & 255;
  }

  int tid = threadIdx.x;
#pragma unroll
  for (int i = 0; i < 8; i++) {
    int L = i * 256 + tid;
    int row = L >> 5, u = L & 31;
    short8 vh = *(const short8*)(Ah + (rb * 64 + row) * 256 + u * 8);
    short8 vl = *(const short8*)(Al + (rb * 64 + row) * 256 + u * 8);
    *(short8*)(&sAh[row * 256 + swz32(u, row) * 8]) = vh;
    *(short8*)(&sAl[row * 256 + swz32(u, row) * 8]) = vl;
  }
#pragma unroll
  for (int i = 0; i < 4; i++) {
    int L = i * 256 + tid;
    int row = L >> 5, u = L & 31;
    short8 vh = *(const short8*)(Bh + (cb * 32 + row) * 256 + u * 8);
    short8 vl = *(const short8*)(Bl + (cb * 32 + row) * 256 + u * 8);
    *(short8*)(&sBh[row * 256 + swz32(u, row) * 8]) = vh;
    *(short8*)(&sBl[row * 256 + swz32(u, row) * 8]) = vl;
  }
  __syncthreads();

  int lane = tid & 63, wave = tid >> 6;
  int n = lane & 15, quad = lane >> 4;
  int wm = wave >> 1, wn = wave & 1;
  f32x4 acc0 = {0.f,0.f,0.f,0.f}, acc1 = {0.f,0.f,0.f,0.f};
#pragma unroll
  for (int kk = 0; kk < 8; kk++) {
    int ra = wm * 32 + n;
    int sa0 = ra * 256 + swz32(kk * 4 + quad, ra) * 8;
    int sa1 = (ra + 16) * 256 + swz32(kk * 4 + quad, ra + 16) * 8;
    short8 a0h = *(const short8*)(&sAh[sa0]);
    short8 a1h = *(const short8*)(&sAh[sa1]);
    short8 a0l = *(const short8*)(&sAl[sa0]);
    short8 a1l = *(const short8*)(&sAl[sa1]);
    int rbB = wn * 16 + n;
    int sb = rbB * 256 + swz32(kk * 4 + quad, rbB) * 8;
    short8 bh = *(const short8*)(&sBh[sb]);
    short8 bl = *(const short8*)(&sBl[sb]);
    acc0 = mfma16(a0h, bh, acc0);
    acc1 = mfma16(a1h, bh, acc1);
    acc0 = mfma16(a0h, bl, acc0);
    acc1 = mfma16(a1h, bl, acc1);
    acc0 = mfma16(a0l, bh, acc0);
    acc1 = mfma16(a1l, bh, acc1);
  }
  int colg = cb * 32 + wn * 16 + n;
  float bcol = biasRow ? 0.0f : bias[colg];
#pragma unroll
  for (int mt = 0; mt < 2; mt++) {
    f32x4 acc = mt ? acc1 : acc0;
#pragma unroll
    for (int r = 0; r < 4; r++) {
      int rowg = rb * 64 + wm * 32 + mt * 16 + quad * 4 + r;
      float bb = biasRow ? bias[rowg] : bcol;
      float q = acc[r] + bb;
      u16 h = f2bf(q);
      Ohi[rowg * ldO + colg] = h;
      if (writeLo) Olo[rowg * ldO + colg] = f2bf(q - bf2f(h));
    }
  }
}

// ---------------- kernel 3: flash attention v2 ----------------
// grid: 512 blocks = 128 q-blocks x 4 key-splits; 256 thr = 4 waves x 16 q-rows each.
// ~180 VGPR/wave (no spill), 2 blocks/CU = 2 waves/SIMD. async global_load_lds staging.
__global__ __launch_bounds__(256, 2) void k_flash(
    const u16* __restrict__ wsu, float* __restrict__ wsf) {
  __shared__ u16 sK[32 * 256];       // 16 KB: 32 keys x 256 d, swizzled (swz32)
  __shared__ u16 sV[256 * 32];       // 16 KB: 256 d x 32 keys (V^T tile), swizzled
  __shared__ u16 sP[4 * 16 * 40];    // 5 KB: per-wave P tile, 16x32 padded to stride 40

  int qb = blockIdx.x >> 2, sp = blockIdx.x & 3;   // sp=blockIdx&3: same split -> same XCD (L2 locality)
  int tid = threadIdx.x, lane = tid & 63, wave = tid >> 6;
  int n = lane & 15, quad = lane >> 4;
  const u16* Qhp = wsu + QH;
  const u16* Qlp = wsu + QL;
  const u16* Kp  = wsu + KH;
  const u16* Vp  = wsu + VTB;

  // Q fragments in registers (A-layout: A[m=n][k=quad*8+j]) hi/lo: 64 VGPRs
  short8 qfh[8], qfl[8];
  int rowQ = qb * 64 + wave * 16 + n;
#pragma unroll
  for (int kk = 0; kk < 8; kk++) {
    qfh[kk] = *(const short8*)(Qhp + rowQ * 256 + kk * 32 + quad * 8);
    qfl[kk] = *(const short8*)(Qlp + rowQ * 256 + kk * 32 + quad * 8);
  }

  // staging geometry (round-invariant): LDS linear fill = wave-uniform base + lane*16
  int krow_base = wave * 2 + (lane >> 5);                       // K row = i*8 + krow_base
  int kgu = (lane & 24) | ((lane & 7) ^ (krow_base & 7));       // inverse-swizzled source unit
  int vd_base = wave * 16 + (lane >> 2);                        // V d = i*64 + vd_base
  int vgu = (lane & 3) ^ ((lane >> 3) & 3);

  f32x4 o[16];
#pragma unroll
  for (int nt = 0; nt < 16; nt++) { o[nt][0]=0.f; o[nt][1]=0.f; o[nt][2]=0.f; o[nt][3]=0.f; }
  float mcur[4], lcur[4];
#pragma unroll
  for (int r = 0; r < 4; r++) { mcur[r] = -1e30f; lcur[r] = 0.f; }

  for (int it = 0; it < 64; it++) {
    int key0 = sp * 2048 + it * 32;
    __syncthreads();
#pragma unroll
    for (int i = 0; i < 4; i++) {
      gl_lds16(Kp + (size_t)(key0 + i * 8 + krow_base) * 256 + kgu * 8,
               &sK[i * 2048 + wave * 512]);
      gl_lds16(Vp + (size_t)(i * 64 + vd_base) * 8192 + key0 + vgu * 8,
               &sV[i * 2048 + wave * 512]);
    }
    __syncthreads();

    // S = Q K^T: 2 n-tiles x 8 ksteps x 2 hi/lo terms = 32 MFMA
    f32x4 s0 = {0.f,0.f,0.f,0.f}, s1 = {0.f,0.f,0.f,0.f};
#pragma unroll
    for (int kk = 0; kk < 8; kk++) {
      int su = swz32(kk * 4 + quad, n) * 8;
      short8 b0 = *(const short8*)(&sK[n * 256 + su]);
      short8 b1 = *(const short8*)(&sK[(n + 16) * 256 + su]);
      s0 = mfma16(qfh[kk], b0, s0);
      s1 = mfma16(qfh[kk], b1, s1);
      s0 = mfma16(qfl[kk], b0, s0);
      s1 = mfma16(qfl[kk], b1, s1);
    }

    // online softmax (always-rescale; alpha==1 when no new max)
    float al[4];
#pragma unroll
    for (int r = 0; r < 4; r++) {
      float v = fmaxf(s0[r], s1[r]);
      v = fmaxf(v, __shfl_xor(v, 1));
      v = fmaxf(v, __shfl_xor(v, 2));
      v = fmaxf(v, __shfl_xor(v, 4));
      v = fmaxf(v, __shfl_xor(v, 8));
      float mn = fmaxf(mcur[r], v);
      al[r] = exp2f((mcur[r] - mn) * LOG2E);
      mcur[r] = mn;
      lcur[r] *= al[r];
    }
#pragma unroll
    for (int nt = 0; nt < 16; nt++) {
      o[nt][0] *= al[0]; o[nt][1] *= al[1]; o[nt][2] *= al[2]; o[nt][3] *= al[3];
    }

    // p = exp(s - m); write P to per-wave LDS (C->A layout transform)
    u16* myP = &sP[wave * 640];
#pragma unroll
    for (int r = 0; r < 4; r++) {
      float p0 = exp2f((s0[r] - mcur[r]) * LOG2E);
      float p1 = exp2f((s1[r] - mcur[r]) * LOG2E);
      lcur[r] += p0 + p1;
      myP[(quad * 4 + r) * 40 + n] = f2bf(p0);
      myP[(quad * 4 + r) * 40 + 16 + n] = f2bf(p1);
    }

    // PV: O[16 x 256] += P[16 x 32] @ V[32 x 256]
    short8 pa = *(const short8*)(&myP[n * 40 + quad * 8]);
#pragma unroll
    for (int nt = 0; nt < 16; nt++) {
      int d = nt * 16 + n;
      short8 vb = *(const short8*)(&sV[d * 32 + (quad ^ ((n >> 1) & 3)) * 8]);
      o[nt] = mfma16(pa, vb, o[nt]);
    }
  }

  // reduce l across the 16 lanes sharing rows
#pragma unroll
  for (int r = 0; r < 4; r++) {
    float v = lcur[r];
    v += __shfl_xor(v, 1); v += __shfl_xor(v, 2);
    v += __shfl_xor(v, 4); v += __shfl_xor(v, 8);
    lcur[r] = v;
  }

  // store unnormalized partials + stats
  float* op = wsf + OPART_F + (size_t)sp * (NT * DH);
  int rowb = qb * 64 + wave * 16;
#pragma unroll
  for (int nt = 0; nt < 16; nt++)
#pragma unroll
    for (int r = 0; r < 4; r++)
      op[(size_t)(rowb + quad * 4 + r) * 256 + nt * 16 + n] = o[nt][r];
  if (n == 0) {
#pragma unroll
    for (int r = 0; r < 4; r++) {
      int row = rowb + quad * 4 + r;
      wsf[MPART_F + sp * NT + row] = mcur[r];
      wsf[LPART_F + sp * NT + row] = lcur[r];
    }
  }
}

// ---------------- kernel 4: combine splits ----------------
__global__ __launch_bounds__(256) void k_combine(
    const float* __restrict__ wsf, float* __restrict__ out) {
  int gid = blockIdx.x * 256 + threadIdx.x;
  int row = gid >> 6, cg = gid & 63;
  float m[4], l[4];
#pragma unroll
  for (int s = 0; s < 4; s++) {
    m[s] = wsf[MPART_F + s * NT + row];
    l[s] = wsf[LPART_F + s * NT + row];
  }
  float ms = fmaxf(fmaxf(m[0], m[1]), fmaxf(m[2], m[3]));
  float denom = 0.f;
  f32x4 acc = {0.f, 0.f, 0.f, 0.f};
#pragma unroll
  for (int s = 0; s < 4; s++) {
    float w = exp2f((m[s] - ms) * LOG2E);
    denom += w * l[s];
    f32x4 ov = *(const f32x4*)(wsf + OPART_F + ((size_t)s * NT + row) * 256 + cg * 4);
    acc[0] += w * ov[0]; acc[1] += w * ov[1];
    acc[2] += w * ov[2]; acc[3] += w * ov[3];
  }
  float inv = 1.0f / denom;
  f32x4 r = {acc[0] * inv, acc[1] * inv, acc[2] * inv, acc[3] * inv};
  *(f32x4*)(out + row * 256 + cg * 4) = r;
}

extern "C" void kernel_launch(void* const* d_in, const int* in_sizes, int n_in,
                              void* d_out, int out_size, void* d_ws, size_t ws_size,
                              hipStream_t stream) {
  const float* x1 = (const float*)d_in[0];
  const float* x2 = (const float*)d_in[1];
  const float* x3 = (const float*)d_in[2];
  const float* Wq = (const float*)d_in[3];
  const float* bq = (const float*)d_in[4];
  const float* Wk = (const float*)d_in[5];
  const float* bk = (const float*)d_in[6];
  const float* Wv = (const float*)d_in[7];
  const float* bv = (const float*)d_in[8];
  u16* wsu = (u16*)d_ws;
  float* wsf = (float*)d_ws;
  float* out = (float*)d_out;

  k_convert<<<dim3(3168), dim3(256), 0, stream>>>(x1, x2, x3, Wq, Wk, Wv, wsu);
  k_qkv<<<dim3(3072), dim3(256), 0, stream>>>(wsu, bq, bk, bv);
  k_flash<<<dim3(512), dim3(256), 0, stream>>>(wsu, wsf);
  k_combine<<<dim3(2048), dim3(256), 0, stream>>>(wsf, out);
}

// Round 4
// 231.662 us; speedup vs baseline: 2.4269x; 1.2303x over previous
//
#include <hip/hip_runtime.h>
#include <stdint.h>

typedef unsigned short u16;
typedef __attribute__((ext_vector_type(8))) short short8;   // 8 bf16 = 4 VGPRs (MFMA A/B frag)
typedef __attribute__((ext_vector_type(4))) float f32x4;    // MFMA C/D frag

#define LOG2E 1.4426950408889634f
#define NT 8192
#define DH 256
#define NSP 8                   // key splits

// ---- workspace layout (u16 element offsets) ----
// persistent across flash:
#define QH     0
#define KH     2097152
#define VTB    4194304          // V transposed: [256][8192]
#define OPARTB 6291456          // 8 x [8192][256] bf16 unnormalized partial O (32 MB)
// temps (dead after k_qkv; deliberately overlap OPARTB region):
#define XH0 6291456
#define XL0 8388608
#define XH1 10485760
#define XL1 12582912
#define XH2 14680064
#define XL2 16777216
#define WQH 18874368
#define WQL 18939904
#define WKH 19005440
#define WKL 19070976
#define WVH 19136512
#define WVL 19202048
// fp32 region (float element offsets), after OPARTB (byte 46,137,344):
#define MPART_F 11534336        // 8 x [8192] per-split softmax base m0
#define LPART_F 11599872        // 8 x [8192] per-split denom
// total ws bytes used: ~46.7 MB

__device__ __forceinline__ u16 f2bf(float f) {
  union { float f; uint32_t u; } c; c.f = f;
  uint32_t u = c.u;
  return (u16)((u + 0x7fffu + ((u >> 16) & 1)) >> 16);   // RNE
}
__device__ __forceinline__ u16 f2bf_hu(float f) {        // round-half-up: 2 VALU ops
  union { float f; uint32_t u; } c; c.f = f;
  return (u16)((c.u + 0x8000u) >> 16);
}
__device__ __forceinline__ float bf2f(u16 h) {
  union { uint32_t u; float f; } c; c.u = ((uint32_t)h) << 16;
  return c.f;
}

// XOR swizzle for LDS rows of 32 16B-units (512B rows)
__device__ __forceinline__ int swz32(int u, int row) {
  return (u & 24) | ((u & 7) ^ (row & 7));
}

__device__ __forceinline__ f32x4 mfma16(short8 a, short8 b, f32x4 c) {
  return __builtin_amdgcn_mfma_f32_16x16x32_bf16(a, b, c, 0, 0, 0);
}

// async global->LDS, 16B per lane; LDS dest is wave-uniform base + lane*16
__device__ __forceinline__ void gl_lds16(const u16* g, u16* l) {
  __builtin_amdgcn_global_load_lds(
      (const __attribute__((address_space(1))) uint32_t*)g,
      (__attribute__((address_space(3))) uint32_t*)l, 16, 0, 0);
}

// ---------------- kernel 1: fp32 -> hi/lo bf16 split ----------------
__global__ __launch_bounds__(256) void k_convert(
    const float* __restrict__ x1, const float* __restrict__ x2, const float* __restrict__ x3,
    const float* __restrict__ wq, const float* __restrict__ wk, const float* __restrict__ wv,
    u16* __restrict__ wsu) {
  int b = blockIdx.x;
  const float* src; u16 *dh, *dl; int bl;
  if (b < 1024)      { src = x1; dh = wsu + XH0; dl = wsu + XL0; bl = b; }
  else if (b < 2048) { src = x2; dh = wsu + XH1; dl = wsu + XL1; bl = b - 1024; }
  else if (b < 3072) { src = x3; dh = wsu + XH2; dl = wsu + XL2; bl = b - 2048; }
  else if (b < 3104) { src = wq; dh = wsu + WQH; dl = wsu + WQL; bl = b - 3072; }
  else if (b < 3136) { src = wk; dh = wsu + WKH; dl = wsu + WKL; bl = b - 3104; }
  else               { src = wv; dh = wsu + WVH; dl = wsu + WVL; bl = b - 3136; }
  int i = (bl * 256 + threadIdx.x) * 8;
  f32x4 a = *(const f32x4*)(src + i);
  f32x4 c = *(const f32x4*)(src + i + 4);
  short8 rh, rl;
  float v[8] = {a[0], a[1], a[2], a[3], c[0], c[1], c[2], c[3]};
#pragma unroll
  for (int j = 0; j < 8; j++) {
    u16 h = f2bf(v[j]);
    rh[j] = (short)h;
    rl[j] = (short)f2bf(v[j] - bf2f(h));
  }
  *(short8*)(dh + i) = rh;
  *(short8*)(dl + i) = rl;
}

// ---------------- kernel 2: QKV projection (NT gemm, 3-term hi/lo bf16 MFMA) ----------------
__global__ __launch_bounds__(256) void k_qkv(
    u16* __restrict__ wsu,
    const float* __restrict__ bq, const float* __restrict__ bk, const float* __restrict__ bv) {
  __shared__ u16 sAh[64 * 256];
  __shared__ u16 sAl[64 * 256];
  __shared__ u16 sBh[32 * 256];
  __shared__ u16 sBl[32 * 256];
  int bx = blockIdx.x;
  int mid = bx >> 10;
  int t = bx & 1023;
  const u16 *Ah, *Al, *Bh, *Bl; u16 *Ohi; const float* bias;
  int rb, cb, ldO, biasRow;
  if (mid == 0) {
    Ah = wsu + XH0; Al = wsu + XL0; Bh = wsu + WQH; Bl = wsu + WQL;
    Ohi = wsu + QH; bias = bq; biasRow = 0; ldO = 256;
    rb = t >> 3; cb = t & 7;
  } else if (mid == 1) {
    Ah = wsu + XH1; Al = wsu + XL1; Bh = wsu + WKH; Bl = wsu + WKL;
    Ohi = wsu + KH; bias = bk; biasRow = 0; ldO = 256;
    rb = t >> 3; cb = t & 7;
  } else {
    Ah = wsu + WVH; Al = wsu + WVL; Bh = wsu + XH2; Bl = wsu + XL2;
    Ohi = wsu + VTB; bias = bv; biasRow = 1; ldO = 8192;
    rb = t >> 8; cb = t & 255;
  }

  int tid = threadIdx.x;
#pragma unroll
  for (int i = 0; i < 8; i++) {
    int L = i * 256 + tid;
    int row = L >> 5, u = L & 31;
    short8 vh = *(const short8*)(Ah + (rb * 64 + row) * 256 + u * 8);
    short8 vl = *(const short8*)(Al + (rb * 64 + row) * 256 + u * 8);
    *(short8*)(&sAh[row * 256 + swz32(u, row) * 8]) = vh;
    *(short8*)(&sAl[row * 256 + swz32(u, row) * 8]) = vl;
  }
#pragma unroll
  for (int i = 0; i < 4; i++) {
    int L = i * 256 + tid;
    int row = L >> 5, u = L & 31;
    short8 vh = *(const short8*)(Bh + (cb * 32 + row) * 256 + u * 8);
    short8 vl = *(const short8*)(Bl + (cb * 32 + row) * 256 + u * 8);
    *(short8*)(&sBh[row * 256 + swz32(u, row) * 8]) = vh;
    *(short8*)(&sBl[row * 256 + swz32(u, row) * 8]) = vl;
  }
  __syncthreads();

  int lane = tid & 63, wave = tid >> 6;
  int n = lane & 15, quad = lane >> 4;
  int wm = wave >> 1, wn = wave & 1;
  f32x4 acc0 = {0.f,0.f,0.f,0.f}, acc1 = {0.f,0.f,0.f,0.f};
#pragma unroll
  for (int kk = 0; kk < 8; kk++) {
    int ra = wm * 32 + n;
    int sa0 = ra * 256 + swz32(kk * 4 + quad, ra) * 8;
    int sa1 = (ra + 16) * 256 + swz32(kk * 4 + quad, ra + 16) * 8;
    short8 a0h = *(const short8*)(&sAh[sa0]);
    short8 a1h = *(const short8*)(&sAh[sa1]);
    short8 a0l = *(const short8*)(&sAl[sa0]);
    short8 a1l = *(const short8*)(&sAl[sa1]);
    int rbB = wn * 16 + n;
    int sb = rbB * 256 + swz32(kk * 4 + quad, rbB) * 8;
    short8 bh = *(const short8*)(&sBh[sb]);
    short8 bl = *(const short8*)(&sBl[sb]);
    acc0 = mfma16(a0h, bh, acc0);
    acc1 = mfma16(a1h, bh, acc1);
    acc0 = mfma16(a0h, bl, acc0);
    acc1 = mfma16(a1h, bl, acc1);
    acc0 = mfma16(a0l, bh, acc0);
    acc1 = mfma16(a1l, bh, acc1);
  }
  int colg = cb * 32 + wn * 16 + n;
  float bcol = biasRow ? 0.0f : bias[colg];
#pragma unroll
  for (int mt = 0; mt < 2; mt++) {
    f32x4 acc = mt ? acc1 : acc0;
#pragma unroll
    for (int r = 0; r < 4; r++) {
      int rowg = rb * 64 + wm * 32 + mt * 16 + quad * 4 + r;
      float bb = biasRow ? bias[rowg] : bcol;
      Ohi[rowg * ldO + colg] = f2bf(acc[r] + bb);
    }
  }
}

// ---------------- kernel 3: flash attention v3 ----------------
// grid: 512 blocks = 64 q-blocks x 8 key-splits; 4 waves x 32 q-rows each.
// Double-buffered K/V (one barrier/iter), fixed-base softmax (no rescale),
// Q bf16-hi in registers. 2 blocks/CU (LDS 74 KB, ~250 VGPR+AGPR).
__global__ __launch_bounds__(256, 2) void k_flash(
    const u16* __restrict__ wsu, u16* __restrict__ opart, float* __restrict__ wsf) {
  __shared__ u16 sK[2][32 * 256];    // 2 x 16 KB
  __shared__ u16 sV[2][256 * 32];    // 2 x 16 KB
  __shared__ u16 sP[4 * 32 * 40];    // 10 KB: per-wave 32x32 P, stride 40

  int qb = blockIdx.x >> 3, sp = blockIdx.x & 7;   // split -> XCD pinning (1 MB K/V per XCD L2)
  int tid = threadIdx.x, lane = tid & 63, wave = tid >> 6;
  int n = lane & 15, quad = lane >> 4;
  const u16* Qp = wsu + QH;
  const u16* Kp = wsu + KH;
  const u16* Vp = wsu + VTB;

  // Q fragments (A-layout: A[m][k=quad*8+j]) for 2 m-tiles: 64 VGPR
  short8 qf[2][8];
  int rowQ0 = qb * 128 + wave * 32 + n;
#pragma unroll
  for (int mt = 0; mt < 2; mt++)
#pragma unroll
    for (int kk = 0; kk < 8; kk++)
      qf[mt][kk] = *(const short8*)(Qp + (size_t)(rowQ0 + mt * 16) * 256 + kk * 32 + quad * 8);

  // staging lane geometry (LDS fill = wave-uniform base + lane*16)
  int krow_base = wave * 2 + (lane >> 5);                  // K row = i*8 + krow_base
  int kgu = (lane & 24) | ((lane & 7) ^ (krow_base & 7));  // inverse-swizzled source unit
  int vd_base = wave * 16 + (lane >> 2);                   // V d = i*64 + vd_base
  int vgu = (lane & 3) ^ ((lane >> 3) & 3);

  int key00 = sp * 1024;

  // prefetch tile 0 into buffer 0
#pragma unroll
  for (int i = 0; i < 4; i++) {
    gl_lds16(Kp + (size_t)(key00 + i * 8 + krow_base) * 256 + kgu * 8,
             &sK[0][i * 2048 + wave * 512]);
    gl_lds16(Vp + (size_t)(i * 64 + vd_base) * 8192 + key00 + vgu * 8,
             &sV[0][i * 2048 + wave * 512]);
  }

  f32x4 o[2][16];
#pragma unroll
  for (int mt = 0; mt < 2; mt++)
#pragma unroll
    for (int nt = 0; nt < 16; nt++) { o[mt][nt][0]=0.f; o[mt][nt][1]=0.f; o[mt][nt][2]=0.f; o[mt][nt][3]=0.f; }
  float negm0L[8], lcur[8];
#pragma unroll
  for (int j = 0; j < 8; j++) { negm0L[j] = 0.f; lcur[j] = 0.f; }

  for (int it = 0; it < 32; it++) {
    __syncthreads();   // drains vmcnt: buf[cur] loads complete; all waves done with buf[cur^1]
    int cur = it & 1;
    if (it + 1 < 32) {
      int k1 = key00 + (it + 1) * 32;
#pragma unroll
      for (int i = 0; i < 4; i++) {
        gl_lds16(Kp + (size_t)(k1 + i * 8 + krow_base) * 256 + kgu * 8,
                 &sK[cur ^ 1][i * 2048 + wave * 512]);
        gl_lds16(Vp + (size_t)(i * 64 + vd_base) * 8192 + k1 + vgu * 8,
                 &sV[cur ^ 1][i * 2048 + wave * 512]);
      }
    }
    const u16* bK = sK[cur];
    const u16* bV = sV[cur];

    // S = Q K^T: 2 m-tiles x 2 n-tiles x 8 ksteps = 32 MFMA (dep distance 4)
    f32x4 s[2][2];
#pragma unroll
    for (int mt = 0; mt < 2; mt++)
#pragma unroll
      for (int ntk = 0; ntk < 2; ntk++) { s[mt][ntk][0]=0.f; s[mt][ntk][1]=0.f; s[mt][ntk][2]=0.f; s[mt][ntk][3]=0.f; }
#pragma unroll
    for (int kk = 0; kk < 8; kk++) {
      int su = swz32(kk * 4 + quad, n) * 8;       // n and n+16 share (row&7) -> same su
      short8 b0 = *(const short8*)(&bK[n * 256 + su]);
      short8 b1 = *(const short8*)(&bK[(n + 16) * 256 + su]);
      s[0][0] = mfma16(qf[0][kk], b0, s[0][0]);
      s[0][1] = mfma16(qf[0][kk], b1, s[0][1]);
      s[1][0] = mfma16(qf[1][kk], b0, s[1][0]);
      s[1][1] = mfma16(qf[1][kk], b1, s[1][1]);
    }

    // fixed softmax base from first tile (no online rescale; logits bounded)
    if (it == 0) {
#pragma unroll
      for (int mt = 0; mt < 2; mt++)
#pragma unroll
        for (int r = 0; r < 4; r++) {
          float v = fmaxf(s[mt][0][r], s[mt][1][r]);
          v = fmaxf(v, __shfl_xor(v, 1));
          v = fmaxf(v, __shfl_xor(v, 2));
          v = fmaxf(v, __shfl_xor(v, 4));
          v = fmaxf(v, __shfl_xor(v, 8));
          negm0L[mt * 4 + r] = -v * LOG2E;
        }
    }

    // p = exp2(s*log2e - m0*log2e), clamped; accumulate l; pack to LDS (C->A transform)
    u16* myP = &sP[wave * 1280];
#pragma unroll
    for (int mt = 0; mt < 2; mt++)
#pragma unroll
      for (int r = 0; r < 4; r++) {
        int j = mt * 4 + r;
        float x0 = fminf(fmaf(s[mt][0][r], LOG2E, negm0L[j]), 110.f);
        float x1 = fminf(fmaf(s[mt][1][r], LOG2E, negm0L[j]), 110.f);
        float p0 = exp2f(x0);
        float p1 = exp2f(x1);
        lcur[j] += p0 + p1;
        int row = mt * 16 + quad * 4 + r;
        myP[row * 40 + n] = f2bf_hu(p0);
        myP[row * 40 + 16 + n] = f2bf_hu(p1);
      }

    // PV: O[32 x 256] += P[32 x 32] @ V[32 x 256]
    short8 pa0 = *(const short8*)(&myP[n * 40 + quad * 8]);
    short8 pa1 = *(const short8*)(&myP[(16 + n) * 40 + quad * 8]);
#pragma unroll
    for (int nt = 0; nt < 16; nt++) {
      int d = nt * 16 + n;
      short8 vb = *(const short8*)(&bV[d * 32 + (quad ^ ((n >> 1) & 3)) * 8]);
      o[0][nt] = mfma16(pa0, vb, o[0][nt]);
      o[1][nt] = mfma16(pa1, vb, o[1][nt]);
    }
  }

  // reduce l across the 16 lanes sharing rows
#pragma unroll
  for (int j = 0; j < 8; j++) {
    float v = lcur[j];
    v += __shfl_xor(v, 1); v += __shfl_xor(v, 2);
    v += __shfl_xor(v, 4); v += __shfl_xor(v, 8);
    lcur[j] = v;
  }

  // store bf16 unnormalized partials + stats
  u16* op = opart + (size_t)sp * (NT * DH);
  int rowb = qb * 128 + wave * 32;
#pragma unroll
  for (int mt = 0; mt < 2; mt++)
#pragma unroll
    for (int nt = 0; nt < 16; nt++)
#pragma unroll
      for (int r = 0; r < 4; r++) {
        int row = rowb + mt * 16 + quad * 4 + r;
        op[(size_t)row * 256 + nt * 16 + n] = f2bf(o[mt][nt][r]);
      }
  if (n == 0) {
#pragma unroll
    for (int j = 0; j < 8; j++) {
      int row = rowb + (j >> 2) * 16 + quad * 4 + (j & 3);
      wsf[MPART_F + sp * NT + row] = negm0L[j] * -0.6931471805599453f;
      wsf[LPART_F + sp * NT + row] = lcur[j];
    }
  }
}

// ---------------- kernel 4: combine 8 splits ----------------
__global__ __launch_bounds__(256) void k_combine(
    const u16* __restrict__ opart, const float* __restrict__ wsf, float* __restrict__ out) {
  int gid = blockIdx.x * 256 + threadIdx.x;
  int row = gid >> 6, cg = gid & 63;
  float m[8], l[8];
#pragma unroll
  for (int s = 0; s < 8; s++) {
    m[s] = wsf[MPART_F + s * NT + row];
    l[s] = wsf[LPART_F + s * NT + row];
  }
  float ms = m[0];
#pragma unroll
  for (int s = 1; s < 8; s++) ms = fmaxf(ms, m[s]);
  float denom = 0.f;
  float acc[4] = {0.f, 0.f, 0.f, 0.f};
#pragma unroll
  for (int s = 0; s < 8; s++) {
    float w = exp2f((m[s] - ms) * LOG2E);
    denom += w * l[s];
    const u16* pp = opart + ((size_t)s * NT + row) * 256 + cg * 4;
    uint2 v = *(const uint2*)pp;
    acc[0] += w * bf2f((u16)(v.x & 0xffff));
    acc[1] += w * bf2f((u16)(v.x >> 16));
    acc[2] += w * bf2f((u16)(v.y & 0xffff));
    acc[3] += w * bf2f((u16)(v.y >> 16));
  }
  float inv = 1.0f / denom;
  f32x4 r = {acc[0] * inv, acc[1] * inv, acc[2] * inv, acc[3] * inv};
  *(f32x4*)(out + (size_t)row * 256 + cg * 4) = r;
}

extern "C" void kernel_launch(void* const* d_in, const int* in_sizes, int n_in,
                              void* d_out, int out_size, void* d_ws, size_t ws_size,
                              hipStream_t stream) {
  const float* x1 = (const float*)d_in[0];
  const float* x2 = (const float*)d_in[1];
  const float* x3 = (const float*)d_in[2];
  const float* Wq = (const float*)d_in[3];
  const float* bq = (const float*)d_in[4];
  const float* Wk = (const float*)d_in[5];
  const float* bk = (const float*)d_in[6];
  const float* Wv = (const float*)d_in[7];
  const float* bv = (const float*)d_in[8];
  u16* wsu = (u16*)d_ws;
  float* wsf = (float*)d_ws;
  float* out = (float*)d_out;

  k_convert<<<dim3(3168), dim3(256), 0, stream>>>(x1, x2, x3, Wq, Wk, Wv, wsu);
  k_qkv<<<dim3(3072), dim3(256), 0, stream>>>(wsu, bq, bk, bv);
  k_flash<<<dim3(512), dim3(256), 0, stream>>>(wsu, wsu + OPARTB, wsf);
  k_combine<<<dim3(2048), dim3(256), 0, stream>>>(wsu + OPARTB, wsf, out);
}